// Round 10
// baseline (2042.443 us; speedup 1.0000x reference)
//
#include <hip/hip_runtime.h>
#include <hip/hip_bf16.h>

typedef unsigned int u32;
typedef unsigned short u16;

struct WPtrs { const void* p[19]; };

// ---- wsW float layout ----
// 0:W1[160] 160:b1[16] 176:W2[256] 432:b2[16] 448:Wz[256] 704:bz[16] 720:Wr[256]
// 976:br[16] 992:Wh[256] 1248:bh[16] 1264:Lz[512] 1776:lz[16] 1792:Lr[512] 2304:lr[16]
// 2320:Lh[512] 2832:lh[16] 2848:att[5] 2853:fcW[32] 2885:fcb[2]
// derived: 2944:Az 3200:Ar 3456:Ah 3712:cz 3728:cr 3744:ch
// packed GRU block at 4096 (1632 floats)

__device__ __forceinline__ float sigm(float x){ return 1.0f/(1.0f+__expf(-x)); }

__device__ __forceinline__ float bflo(u32 u){ return __uint_as_float(u << 16); }
__device__ __forceinline__ float bfhi(u32 u){ return __uint_as_float(u & 0xffff0000u); }
__device__ __forceinline__ u32 packbf(float a, float b){
    u32 ua = __float_as_uint(a), ub = __float_as_uint(b);
    ua += 0x7fffu + ((ua >> 16) & 1u);
    ub += 0x7fffu + ((ub >> 16) & 1u);
    return (ua >> 16) | (ub & 0xffff0000u);
}

__global__ __launch_bounds__(256)
void k_prep(const void* __restrict__ x, WPtrs wp, int* __restrict__ flagp,
            float* __restrict__ wsW)
{
    __shared__ int scount;
    __shared__ int sflag;
    if (threadIdx.x == 0) scount = 0;
    __syncthreads();
    const u16* xs = (const u16*)x;
    int cnt = 0;
    #pragma unroll
    for (int j = 0; j < 8; j++) {
        int k = (threadIdx.x*8 + j) * 1201;
        u16 u = xs[2*k];
        int ex = (u >> 7) & 0xFF;
        cnt += (ex >= 110 && ex <= 140) ? 1 : 0;
    }
    atomicAdd(&scount, cnt);
    __syncthreads();
    if (threadIdx.x == 0) { sflag = (scount > 1024) ? 1 : 0; flagp[0] = sflag; }
    __syncthreads();
    const int flag = sflag;

    const int sizes[19] = {160,16,256,16,256,16,256,16,256,16,512,16,512,16,512,16,5,32,2};
    int off = 0;
    for (int a = 0; a < 19; a++) {
        const void* s = wp.p[a];
        for (int j = threadIdx.x; j < sizes[a]; j += 256) {
            float v = flag ? __bfloat162float(((const __hip_bfloat16*)s)[j])
                           : ((const float*)s)[j];
            wsW[off + j] = v;
        }
        off += sizes[a];
    }
    __syncthreads();
    {
        int k = threadIdx.x >> 4, j = threadIdx.x & 15;
        float az = 0.f, ar = 0.f, ah = 0.f;
        #pragma unroll
        for (int m = 0; m < 16; m++) {
            az += wsW[448 + k*16 + m] * wsW[1264 + m*16 + j];
            ar += wsW[720 + k*16 + m] * wsW[1792 + m*16 + j];
            ah += wsW[992 + k*16 + m] * wsW[2320 + m*16 + j];
        }
        wsW[2944 + threadIdx.x] = az;
        wsW[3200 + threadIdx.x] = ar;
        wsW[3456 + threadIdx.x] = ah;
        if (threadIdx.x < 16) {
            float cz = wsW[1776 + j], cr = wsW[2304 + j], ch = wsW[2832 + j];
            #pragma unroll
            for (int m = 0; m < 16; m++) {
                cz += wsW[704  + m] * wsW[1264 + m*16 + j];
                cr += wsW[976  + m] * wsW[1792 + m*16 + j];
                ch += wsW[1248 + m] * wsW[2320 + m*16 + j];
            }
            wsW[3712 + j] = cz; wsW[3728 + j] = cr; wsW[3744 + j] = ch;
        }
    }
    __syncthreads();
    {
        int j = threadIdx.x;
        wsW[4096 +        j] = wsW[2944 + j];   // Az
        wsW[4096 +  256 + j] = wsW[3200 + j];   // Ar
        wsW[4096 +  512 + j] = wsW[3456 + j];   // Ah
        wsW[4096 +  768 + j] = wsW[1520 + j];   // Lz bottom (rows 16..31)
        wsW[4096 + 1024 + j] = wsW[2048 + j];   // Lr bottom
        wsW[4096 + 1280 + j] = wsW[2576 + j];   // Lh bottom
        if (j < 16) {
            wsW[4096 + 1536 + j] = wsW[3712 + j];
            wsW[4096 + 1552 + j] = wsW[3728 + j];
            wsW[4096 + 1568 + j] = wsW[3744 + j];
        }
        if (j < 32) wsW[4096 + 1592 + j] = wsW[2853 + j];
        if (j < 2)  wsW[4096 + 1624 + j] = wsW[2885 + j];
        if (j == 0) {
            float a0=wsW[2848],a1=wsW[2849],a2=wsW[2850],a3=wsW[2851],a4=wsW[2852];
            float am = fmaxf(fmaxf(fmaxf(a0,a1),fmaxf(a2,a3)),a4);
            float e0=__expf(a0-am),e1=__expf(a1-am),e2=__expf(a2-am),
                  e3=__expf(a3-am),e4=__expf(a4-am);
            float inv = 1.f/(e0+e1+e2+e3+e4);
            wsW[4096+1584+0]=e0*inv; wsW[4096+1584+1]=e1*inv;
            wsW[4096+1584+2]=e2*inv; wsW[4096+1584+3]=e3*inv;
            wsW[4096+1584+4]=e4*inv;
        }
    }
}

__global__ __launch_bounds__(256)
void k_deg(const int* __restrict__ dst, int* __restrict__ deg, int E)
{
    int e = blockIdx.x*256 + threadIdx.x;
    if (e < E) atomicAdd(&deg[dst[e]], 1);
}

__global__ __launch_bounds__(256)
void k_scan_a(const int* __restrict__ deg, float* __restrict__ dis,
              float* __restrict__ dinv, int* __restrict__ bsum, int N)
{
    __shared__ int sm[256];
    int i = blockIdx.x*256 + threadIdx.x;
    int c = (i < N) ? deg[i] : 0;
    if (i < N) {
        float d = (float)(c + 1);
        dis[i]  = rsqrtf(d);
        dinv[i] = 1.0f / d;
    }
    sm[threadIdx.x] = c; __syncthreads();
    for (int s = 128; s > 0; s >>= 1) {
        if (threadIdx.x < s) sm[threadIdx.x] += sm[threadIdx.x + s];
        __syncthreads();
    }
    if (threadIdx.x == 0) bsum[blockIdx.x] = sm[0];
}

__global__ void k_scan_b(const int* __restrict__ bsum, int* __restrict__ boff, int nb)
{
    __shared__ int sm[512];
    int t = threadIdx.x;
    int v = (t < nb) ? bsum[t] : 0;
    sm[t] = v; __syncthreads();
    for (int s = 1; s < 512; s <<= 1) {
        int add = (t >= s) ? sm[t - s] : 0;
        __syncthreads();
        sm[t] += add;
        __syncthreads();
    }
    if (t < nb) boff[t] = sm[t] - v;   // exclusive
}

__global__ __launch_bounds__(256)
void k_scan_c(const int* __restrict__ deg, const int* __restrict__ boff,
              int* __restrict__ row_start, int* __restrict__ cursor, int N, int E)
{
    __shared__ int sm[256];
    int t = threadIdx.x;
    int i = blockIdx.x*256 + t;
    int c = (i < N) ? deg[i] : 0;
    sm[t] = c; __syncthreads();
    for (int s = 1; s < 256; s <<= 1) {
        int add = (t >= s) ? sm[t - s] : 0;
        __syncthreads();
        sm[t] += add;
        __syncthreads();
    }
    int rs = boff[blockIdx.x] + sm[t] - c;
    if (i < N) {
        row_start[i] = rs;
        cursor[i]    = rs;
        if (i == N - 1) row_start[N] = rs + c;
    }
}

__global__ __launch_bounds__(256)
void k_fill(const int* __restrict__ src, const int* __restrict__ dst,
            const float* __restrict__ dis, int* __restrict__ cursor,
            int2* __restrict__ csr, int E)
{
    int e = blockIdx.x*256 + threadIdx.x;
    if (e < E) {
        int s = src[e], d = dst[e];
        int pos = atomicAdd(&cursor[d], 1);
        csr[pos] = make_int2(s, __float_as_int(dis[s]));
    }
}

// repack x [t][N][10] (bf16 or f32) -> xr bf16-packed [i][50] (25 u32 rows)
__global__ __launch_bounds__(256, 4)
void k_repack(const void* __restrict__ x, const int* __restrict__ flagp,
              u32* __restrict__ xr, int N)
{
    int tid = blockIdx.x*256 + threadIdx.x;
    if (tid >= N*5) return;
    int i = tid / 5, t = tid - i*5;
    u32 o[5];
    if (flagp[0]) {
        const u32* xb = (const u32*)x;
        size_t b = ((size_t)t*N + i)*5;
        #pragma unroll
        for (int m = 0; m < 5; m++) o[m] = xb[b + m];
    } else {
        const float* xf = (const float*)x + ((size_t)t*N + i)*10;
        #pragma unroll
        for (int m = 0; m < 5; m++) o[m] = packbf(xf[2*m], xf[2*m+1]);
    }
    u32* orow = xr + (size_t)i*25 + t*5;
    #pragma unroll
    for (int m = 0; m < 5; m++) orow[m] = o[m];
}

// accumulate a preloaded 5-u32 chunk (10 bf16) scaled by wg
__device__ __forceinline__ void acc10(const u32* __restrict__ u, float wg,
                                      float* __restrict__ acc)
{
    #pragma unroll
    for (int m = 0; m < 5; m++) {
        acc[2*m]   += wg*bflo(u[m]);
        acc[2*m+1] += wg*bfhi(u[m]);
    }
}

// pass 1: per (node i, slice t), i-major. gather xr then relu(@W1+b1) -> bufA bf16 [i][80]
__global__ __launch_bounds__(256, 4)
void k_g1(const u32* __restrict__ xr, const float* __restrict__ dis,
          const float* __restrict__ dinv, const int* __restrict__ row_start,
          const int2* __restrict__ csr, const float* __restrict__ wsW,
          u32* __restrict__ B, int N)
{
    __shared__ float w[176];
    for (int j = threadIdx.x; j < 176; j += 256) w[j] = wsW[j];
    __syncthreads();
    int tid = blockIdx.x*256 + threadIdx.x;
    if (tid >= N*5) return;
    int i = tid / 5, t = tid - i*5;

    float acc[10];
    float dd = dis[i], di = dinv[i];
    int rs = row_start[i], re = row_start[i+1];

    {
        const u32* p = xr + (size_t)i*25 + t*5;
        #pragma unroll
        for (int m = 0; m < 5; m++) {
            u32 u = p[m];
            acc[2*m]   = di*bflo(u);
            acc[2*m+1] = di*bfhi(u);
        }
    }
    int k = rs;
    for (; k + 3 < re; k += 4) {
        int2 s0 = csr[k], s1 = csr[k+1], s2 = csr[k+2], s3 = csr[k+3];
        float w0 = dd*__int_as_float(s0.y), w1 = dd*__int_as_float(s1.y);
        float w2 = dd*__int_as_float(s2.y), w3 = dd*__int_as_float(s3.y);
        const u32* p0 = xr + (size_t)s0.x*25 + t*5;
        const u32* p1 = xr + (size_t)s1.x*25 + t*5;
        const u32* p2 = xr + (size_t)s2.x*25 + t*5;
        const u32* p3 = xr + (size_t)s3.x*25 + t*5;
        u32 u0[5], u1[5], u2[5], u3[5];
        #pragma unroll
        for (int m = 0; m < 5; m++) u0[m] = p0[m];
        #pragma unroll
        for (int m = 0; m < 5; m++) u1[m] = p1[m];
        #pragma unroll
        for (int m = 0; m < 5; m++) u2[m] = p2[m];
        #pragma unroll
        for (int m = 0; m < 5; m++) u3[m] = p3[m];
        acc10(u0, w0, acc); acc10(u1, w1, acc);
        acc10(u2, w2, acc); acc10(u3, w3, acc);
    }
    for (; k < re; k++) {
        int2 sw = csr[k];
        float wg = dd * __int_as_float(sw.y);
        const u32* p = xr + (size_t)sw.x*25 + t*5;
        u32 u[5];
        #pragma unroll
        for (int m = 0; m < 5; m++) u[m] = p[m];
        acc10(u, wg, acc);
    }

    float hh[16];
    #pragma unroll
    for (int jb = 0; jb < 4; jb++) {
        float4 h = ((const float4*)&w[160])[jb];
        #pragma unroll
        for (int f = 0; f < 10; f++) {
            float4 wv = ((const float4*)w)[f*4 + jb];
            h.x += acc[f]*wv.x; h.y += acc[f]*wv.y;
            h.z += acc[f]*wv.z; h.w += acc[f]*wv.w;
        }
        hh[jb*4+0] = fmaxf(h.x, 0.f); hh[jb*4+1] = fmaxf(h.y, 0.f);
        hh[jb*4+2] = fmaxf(h.z, 0.f); hh[jb*4+3] = fmaxf(h.w, 0.f);
    }
    u32* orow = B + (size_t)i*40 + t*8;
    uint4 o0 = make_uint4(packbf(hh[0],hh[1]), packbf(hh[2],hh[3]),
                          packbf(hh[4],hh[5]), packbf(hh[6],hh[7]));
    uint4 o1 = make_uint4(packbf(hh[8],hh[9]), packbf(hh[10],hh[11]),
                          packbf(hh[12],hh[13]), packbf(hh[14],hh[15]));
    ((uint4*)orow)[0] = o0;
    ((uint4*)orow)[1] = o1;
}

// accumulate a preloaded 32B chunk (16 bf16 in 2 uint4) scaled by wg
__device__ __forceinline__ void acc_pair(uint4 a, uint4 b, float wg,
                                         float* __restrict__ acc)
{
    acc[0] += wg*bflo(a.x); acc[1] += wg*bfhi(a.x);
    acc[2] += wg*bflo(a.y); acc[3] += wg*bfhi(a.y);
    acc[4] += wg*bflo(a.z); acc[5] += wg*bfhi(a.z);
    acc[6] += wg*bflo(a.w); acc[7] += wg*bfhi(a.w);
    acc[8]  += wg*bflo(b.x); acc[9]  += wg*bfhi(b.x);
    acc[10] += wg*bflo(b.y); acc[11] += wg*bfhi(b.y);
    acc[12] += wg*bflo(b.z); acc[13] += wg*bfhi(b.z);
    acc[14] += wg*bflo(b.w); acc[15] += wg*bfhi(b.w);
}

// generic unroll-4 gather of 16-feature slice chunks from bf16 rows [i][80]
__device__ __forceinline__ void gather16(const u32* __restrict__ Fin,
                                         const int2* __restrict__ csr,
                                         int rs, int re, int t, float dd,
                                         float* __restrict__ acc)
{
    int k = rs;
    for (; k + 3 < re; k += 4) {
        int2 s0 = csr[k], s1 = csr[k+1], s2 = csr[k+2], s3 = csr[k+3];
        float w0 = dd*__int_as_float(s0.y), w1 = dd*__int_as_float(s1.y);
        float w2 = dd*__int_as_float(s2.y), w3 = dd*__int_as_float(s3.y);
        const uint4* p0 = (const uint4*)(Fin + (size_t)s0.x*40 + t*8);
        const uint4* p1 = (const uint4*)(Fin + (size_t)s1.x*40 + t*8);
        const uint4* p2 = (const uint4*)(Fin + (size_t)s2.x*40 + t*8);
        const uint4* p3 = (const uint4*)(Fin + (size_t)s3.x*40 + t*8);
        uint4 a0 = p0[0], b0 = p0[1];
        uint4 a1 = p1[0], b1 = p1[1];
        uint4 a2 = p2[0], b2 = p2[1];
        uint4 a3 = p3[0], b3 = p3[1];
        acc_pair(a0, b0, w0, acc); acc_pair(a1, b1, w1, acc);
        acc_pair(a2, b2, w2, acc); acc_pair(a3, b3, w3, acc);
    }
    for (; k < re; k++) {
        int2 sw = csr[k];
        float wg = dd*__int_as_float(sw.y);
        const uint4* p = (const uint4*)(Fin + (size_t)sw.x*40 + t*8);
        uint4 a = p[0], b = p[1];
        acc_pair(a, b, wg, acc);
    }
}

// pass 2: per (i,t): gather bf16 [i][80], relu(@W2+b2) -> bf16 [i][80]
__global__ __launch_bounds__(256, 4)
void k_g2(const u32* __restrict__ Fin, const float* __restrict__ dis,
          const float* __restrict__ dinv, const int* __restrict__ row_start,
          const int2* __restrict__ csr, const float* __restrict__ wsW,
          u32* __restrict__ B, int N)
{
    __shared__ float w[272];
    for (int j = threadIdx.x; j < 272; j += 256) w[j] = wsW[176 + j];
    __syncthreads();
    int tid = blockIdx.x*256 + threadIdx.x;
    if (tid >= N*5) return;
    int i = tid / 5, t = tid - i*5;

    float dd = dis[i], di = dinv[i];
    int rs = row_start[i], re = row_start[i+1];

    float acc[16];
    #pragma unroll
    for (int j = 0; j < 16; j++) acc[j] = 0.f;
    {
        const uint4* p = (const uint4*)(Fin + (size_t)i*40 + t*8);
        acc_pair(p[0], p[1], di, acc);
    }
    gather16(Fin, csr, rs, re, t, dd, acc);

    float hh[16];
    #pragma unroll
    for (int jb = 0; jb < 4; jb++) {
        float4 h = ((const float4*)&w[256])[jb];
        #pragma unroll
        for (int f = 0; f < 16; f++) {
            float4 wv = ((const float4*)w)[f*4 + jb];
            h.x += acc[f]*wv.x; h.y += acc[f]*wv.y;
            h.z += acc[f]*wv.z; h.w += acc[f]*wv.w;
        }
        hh[jb*4+0] = fmaxf(h.x, 0.f); hh[jb*4+1] = fmaxf(h.y, 0.f);
        hh[jb*4+2] = fmaxf(h.z, 0.f); hh[jb*4+3] = fmaxf(h.w, 0.f);
    }
    u32* orow = B + (size_t)i*40 + t*8;
    uint4 o0 = make_uint4(packbf(hh[0],hh[1]), packbf(hh[2],hh[3]),
                          packbf(hh[4],hh[5]), packbf(hh[6],hh[7]));
    uint4 o1 = make_uint4(packbf(hh[8],hh[9]), packbf(hh[10],hh[11]),
                          packbf(hh[12],hh[13]), packbf(hh[14],hh[15]));
    ((uint4*)orow)[0] = o0;
    ((uint4*)orow)[1] = o1;
}

// pass 3: per (i,t): gather bf16 [i][80] -> bf16 [i][80]
__global__ __launch_bounds__(256, 4)
void k_g3(const u32* __restrict__ Fin, const float* __restrict__ dis,
          const float* __restrict__ dinv, const int* __restrict__ row_start,
          const int2* __restrict__ csr, u32* __restrict__ B, int N)
{
    int tid = blockIdx.x*256 + threadIdx.x;
    if (tid >= N*5) return;
    int i = tid / 5, t = tid - i*5;

    float dd = dis[i], di = dinv[i];
    int rs = row_start[i], re = row_start[i+1];

    float acc[16];
    #pragma unroll
    for (int j = 0; j < 16; j++) acc[j] = 0.f;
    {
        const uint4* p = (const uint4*)(Fin + (size_t)i*40 + t*8);
        acc_pair(p[0], p[1], di, acc);
    }
    gather16(Fin, csr, rs, re, t, dd, acc);

    u32* orow = B + (size_t)i*40 + t*8;
    uint4 o0 = make_uint4(packbf(acc[0],acc[1]), packbf(acc[2],acc[3]),
                          packbf(acc[4],acc[5]), packbf(acc[6],acc[7]));
    uint4 o1 = make_uint4(packbf(acc[8],acc[9]), packbf(acc[10],acc[11]),
                          packbf(acc[12],acc[13]), packbf(acc[14],acc[15]));
    ((uint4*)orow)[0] = o0;
    ((uint4*)orow)[1] = o1;
}

// GRU + attention + FC + log_softmax. One thread per node; Pf bf16 [i][80].
__global__ __launch_bounds__(256, 3)
void k_gru(const u32* __restrict__ C, const float* __restrict__ wsW,
           const int* __restrict__ flagp, void* __restrict__ out, int N)
{
    __shared__ __align__(16) float sm[1632];
    for (int j = threadIdx.x; j < 1632; j += 256) sm[j] = wsW[4096 + j];
    __syncthreads();

    int i = blockIdx.x*256 + threadIdx.x;
    if (i >= N) return;

    const float4* Az = (const float4*)&sm[0];
    const float4* Ar = (const float4*)&sm[256];
    const float4* Ah = (const float4*)&sm[512];
    const float4* Lz = (const float4*)&sm[768];
    const float4* Lr = (const float4*)&sm[1024];
    const float4* Lh = (const float4*)&sm[1280];

    float H[16];
    #pragma unroll
    for (int j = 0; j < 16; j++) H[j] = 0.f;
    float z0 = sm[1624], z1 = sm[1625];

    for (int t = 0; t < 5; t++) {
        float pf[16];
        {
            const u32* p = C + (size_t)i*40 + t*8;
            uint4 a = ((const uint4*)p)[0];
            uint4 b = ((const uint4*)p)[1];
            pf[0]=bflo(a.x); pf[1]=bfhi(a.x); pf[2]=bflo(a.y); pf[3]=bfhi(a.y);
            pf[4]=bflo(a.z); pf[5]=bfhi(a.z); pf[6]=bflo(a.w); pf[7]=bfhi(a.w);
            pf[8]=bflo(b.x); pf[9]=bfhi(b.x); pf[10]=bflo(b.y); pf[11]=bfhi(b.y);
            pf[12]=bflo(b.z); pf[13]=bfhi(b.z); pf[14]=bflo(b.w); pf[15]=bfhi(b.w);
        }

        float Zg[16];
        #pragma unroll
        for (int jb = 0; jb < 4; jb++) {
            float4 a = ((const float4*)&sm[1536])[jb];
            #pragma unroll
            for (int k = 0; k < 16; k++) {
                float pp = pf[k]; float4 wv = Az[k*4+jb];
                a.x += pp*wv.x; a.y += pp*wv.y; a.z += pp*wv.z; a.w += pp*wv.w;
            }
            #pragma unroll
            for (int k = 0; k < 16; k++) {
                float h = H[k]; float4 wv = Lz[k*4+jb];
                a.x += h*wv.x; a.y += h*wv.y; a.z += h*wv.z; a.w += h*wv.w;
            }
            Zg[jb*4+0]=sigm(a.x); Zg[jb*4+1]=sigm(a.y);
            Zg[jb*4+2]=sigm(a.z); Zg[jb*4+3]=sigm(a.w);
        }
        float HR[16];
        #pragma unroll
        for (int jb = 0; jb < 4; jb++) {
            float4 a = ((const float4*)&sm[1552])[jb];
            #pragma unroll
            for (int k = 0; k < 16; k++) {
                float pp = pf[k]; float4 wv = Ar[k*4+jb];
                a.x += pp*wv.x; a.y += pp*wv.y; a.z += pp*wv.z; a.w += pp*wv.w;
            }
            #pragma unroll
            for (int k = 0; k < 16; k++) {
                float h = H[k]; float4 wv = Lr[k*4+jb];
                a.x += h*wv.x; a.y += h*wv.y; a.z += h*wv.z; a.w += h*wv.w;
            }
            HR[jb*4+0]=H[jb*4+0]*sigm(a.x); HR[jb*4+1]=H[jb*4+1]*sigm(a.y);
            HR[jb*4+2]=H[jb*4+2]*sigm(a.z); HR[jb*4+3]=H[jb*4+3]*sigm(a.w);
        }
        #pragma unroll
        for (int jb = 0; jb < 4; jb++) {
            float4 a = ((const float4*)&sm[1568])[jb];
            #pragma unroll
            for (int k = 0; k < 16; k++) {
                float pp = pf[k]; float4 wv = Ah[k*4+jb];
                a.x += pp*wv.x; a.y += pp*wv.y; a.z += pp*wv.z; a.w += pp*wv.w;
            }
            #pragma unroll
            for (int k = 0; k < 16; k++) {
                float h = HR[k]; float4 wv = Lh[k*4+jb];
                a.x += h*wv.x; a.y += h*wv.y; a.z += h*wv.z; a.w += h*wv.w;
            }
            #pragma unroll
            for (int q = 0; q < 4; q++) {
                int j = jb*4 + q;
                float v = (q==0)?a.x:(q==1)?a.y:(q==2)?a.z:a.w;
                v = fminf(fmaxf(v, -15.f), 15.f);
                float ex = __expf(2.f*v);
                float th = (ex - 1.f) / (ex + 1.f);
                float z = Zg[j];
                H[j] = z*H[j] + (1.f - z)*th;
            }
        }
        float pr = sm[1584 + t];
        float s0 = 0.f, s1 = 0.f;
        #pragma unroll
        for (int k = 0; k < 16; k++) {
            s0 += H[k]*sm[1592 + k*2];
            s1 += H[k]*sm[1592 + k*2 + 1];
        }
        z0 += pr*s0; z1 += pr*s1;
    }

    float mm = fmaxf(z0, z1);
    float l  = __logf(__expf(z0-mm) + __expf(z1-mm));
    float o0 = z0 - mm - l, o1 = z1 - mm - l;
    if (flagp[0]) {
        ((u32*)out)[i] = packbf(o0, o1);
    } else {
        ((float2*)out)[i] = make_float2(o0, o1);
    }
}

extern "C" void kernel_launch(void* const* d_in, const int* in_sizes, int n_in,
                              void* d_out, int out_size, void* d_ws, size_t ws_size,
                              hipStream_t stream)
{
    const void* x   = d_in[0];
    const int* src  = (const int*)d_in[1];
    const int* dst  = (const int*)d_in[2];
    int N = in_sizes[0] / 50;     // T*F_IN = 50
    int E = in_sizes[1];

    char* ws = (char*)d_ws;
    size_t off = 0;
    auto alloc = [&](size_t bytes) -> void* {
        void* p = ws + off;
        off = (off + bytes + 255) & ~(size_t)255;
        return p;
    };
    int*   flagp     = (int*)  alloc(64);
    float* wsW       = (float*)alloc(8192*4);
    int*   deg       = (int*)  alloc((size_t)N*4);
    float* dis       = (float*)alloc((size_t)N*4);
    float* dinv      = (float*)alloc((size_t)N*4);
    int*   row_start = (int*)  alloc(((size_t)N+1)*4);
    int*   cursor    = (int*)  alloc((size_t)N*4);
    int*   bsum      = (int*)  alloc(4096);
    int*   boff      = (int*)  alloc(4096);
    int2*  csr       = (int2*) alloc((size_t)E*8);
    u32*   xr        = (u32*)  alloc((size_t)N*25*4);   // bf16-packed x rows [i][50]
    u32*   bufA      = (u32*)  alloc((size_t)N*40*4);   // bf16-packed [i][80]
    u32*   bufB      = (u32*)  alloc((size_t)N*40*4);
    u32*   bufC      = (u32*)  alloc((size_t)N*40*4);

    int nb  = (N + 255) / 256;
    int gE  = (E + 255) / 256;
    int g5  = ((size_t)N*5 + 255) / 256;

    hipMemsetAsync(deg, 0, (size_t)N*4, stream);

    WPtrs wp;
    for (int a = 0; a < 19; a++) wp.p[a] = d_in[3 + a];
    k_prep<<<1, 256, 0, stream>>>(x, wp, flagp, wsW);

    k_deg   <<<gE, 256, 0, stream>>>(dst, deg, E);
    k_scan_a<<<nb, 256, 0, stream>>>(deg, dis, dinv, bsum, N);
    k_scan_b<<<1, 512, 0, stream>>>(bsum, boff, nb);
    k_scan_c<<<nb, 256, 0, stream>>>(deg, boff, row_start, cursor, N, E);
    k_fill  <<<gE, 256, 0, stream>>>(src, dst, dis, cursor, csr, E);

    k_repack<<<g5, 256, 0, stream>>>(x, flagp, xr, N);
    k_g1    <<<g5, 256, 0, stream>>>(xr, dis, dinv, row_start, csr, wsW, bufA, N);
    k_g2    <<<g5, 256, 0, stream>>>(bufA, dis, dinv, row_start, csr, wsW, bufB, N);
    k_g3    <<<g5, 256, 0, stream>>>(bufB, dis, dinv, row_start, csr, bufC, N);
    k_gru   <<<nb, 256, 0, stream>>>(bufC, wsW, flagp, d_out, N);
}

// Round 11
// 1974.586 us; speedup vs baseline: 1.0344x; 1.0344x over previous
//
#include <hip/hip_runtime.h>
#include <hip/hip_bf16.h>

typedef unsigned int u32;
typedef unsigned short u16;

struct WPtrs { const void* p[19]; };

// ---- wsW float layout ----
// 0:W1[160] 160:b1[16] 176:W2[256] 432:b2[16] 448:Wz[256] 704:bz[16] 720:Wr[256]
// 976:br[16] 992:Wh[256] 1248:bh[16] 1264:Lz[512] 1776:lz[16] 1792:Lr[512] 2304:lr[16]
// 2320:Lh[512] 2832:lh[16] 2848:att[5] 2853:fcW[32] 2885:fcb[2]
// derived: 2944:Az 3200:Ar 3456:Ah 3712:cz 3728:cr 3744:ch
// packed GRU block at 4096 (1632 floats)

__device__ __forceinline__ float sigm(float x){ return 1.0f/(1.0f+__expf(-x)); }

__device__ __forceinline__ float bflo(u32 u){ return __uint_as_float(u << 16); }
__device__ __forceinline__ float bfhi(u32 u){ return __uint_as_float(u & 0xffff0000u); }
__device__ __forceinline__ u32 packbf(float a, float b){
    u32 ua = __float_as_uint(a), ub = __float_as_uint(b);
    ua += 0x7fffu + ((ua >> 16) & 1u);
    ub += 0x7fffu + ((ub >> 16) & 1u);
    return (ua >> 16) | (ub & 0xffff0000u);
}

// manual e4m3 (bias 7) codec via f32 exponent-shift trick
__device__ __forceinline__ float f8dec(u32 b){
    float mag = __uint_as_float((b & 0x7fu) << 20) * __uint_as_float(247u << 23); // *2^120
    return __uint_as_float(__float_as_uint(mag) | ((b & 0x80u) << 24));
}
__device__ __forceinline__ u32 f8enc(float x){
    u32 xb = __float_as_uint(x);
    u32 s = (xb >> 24) & 0x80u;
    float ax = __uint_as_float(xb & 0x7fffffffu) * __uint_as_float(7u << 23);    // *2^-120
    u32 em = (__float_as_uint(ax) + 0x80000u) >> 20;
    if (em > 0x7Eu) em = 0x7Eu;
    return s | em;
}
__device__ __forceinline__ u32 f8pack4(float a, float b, float c, float d){
    return f8enc(a) | (f8enc(b) << 8) | (f8enc(c) << 16) | (f8enc(d) << 24);
}

__global__ __launch_bounds__(256)
void k_prep(const void* __restrict__ x, WPtrs wp, int* __restrict__ flagp,
            float* __restrict__ wsW)
{
    __shared__ int scount;
    __shared__ int sflag;
    if (threadIdx.x == 0) scount = 0;
    __syncthreads();
    const u16* xs = (const u16*)x;
    int cnt = 0;
    #pragma unroll
    for (int j = 0; j < 8; j++) {
        int k = (threadIdx.x*8 + j) * 1201;
        u16 u = xs[2*k];
        int ex = (u >> 7) & 0xFF;
        cnt += (ex >= 110 && ex <= 140) ? 1 : 0;
    }
    atomicAdd(&scount, cnt);
    __syncthreads();
    if (threadIdx.x == 0) { sflag = (scount > 1024) ? 1 : 0; flagp[0] = sflag; }
    __syncthreads();
    const int flag = sflag;

    const int sizes[19] = {160,16,256,16,256,16,256,16,256,16,512,16,512,16,512,16,5,32,2};
    int off = 0;
    for (int a = 0; a < 19; a++) {
        const void* s = wp.p[a];
        for (int j = threadIdx.x; j < sizes[a]; j += 256) {
            float v = flag ? __bfloat162float(((const __hip_bfloat16*)s)[j])
                           : ((const float*)s)[j];
            wsW[off + j] = v;
        }
        off += sizes[a];
    }
    __syncthreads();
    {
        int k = threadIdx.x >> 4, j = threadIdx.x & 15;
        float az = 0.f, ar = 0.f, ah = 0.f;
        #pragma unroll
        for (int m = 0; m < 16; m++) {
            az += wsW[448 + k*16 + m] * wsW[1264 + m*16 + j];
            ar += wsW[720 + k*16 + m] * wsW[1792 + m*16 + j];
            ah += wsW[992 + k*16 + m] * wsW[2320 + m*16 + j];
        }
        wsW[2944 + threadIdx.x] = az;
        wsW[3200 + threadIdx.x] = ar;
        wsW[3456 + threadIdx.x] = ah;
        if (threadIdx.x < 16) {
            float cz = wsW[1776 + j], cr = wsW[2304 + j], ch = wsW[2832 + j];
            #pragma unroll
            for (int m = 0; m < 16; m++) {
                cz += wsW[704  + m] * wsW[1264 + m*16 + j];
                cr += wsW[976  + m] * wsW[1792 + m*16 + j];
                ch += wsW[1248 + m] * wsW[2320 + m*16 + j];
            }
            wsW[3712 + j] = cz; wsW[3728 + j] = cr; wsW[3744 + j] = ch;
        }
    }
    __syncthreads();
    {
        int j = threadIdx.x;
        wsW[4096 +        j] = wsW[2944 + j];   // Az
        wsW[4096 +  256 + j] = wsW[3200 + j];   // Ar
        wsW[4096 +  512 + j] = wsW[3456 + j];   // Ah
        wsW[4096 +  768 + j] = wsW[1520 + j];   // Lz bottom (rows 16..31)
        wsW[4096 + 1024 + j] = wsW[2048 + j];   // Lr bottom
        wsW[4096 + 1280 + j] = wsW[2576 + j];   // Lh bottom
        if (j < 16) {
            wsW[4096 + 1536 + j] = wsW[3712 + j];
            wsW[4096 + 1552 + j] = wsW[3728 + j];
            wsW[4096 + 1568 + j] = wsW[3744 + j];
        }
        if (j < 32) wsW[4096 + 1592 + j] = wsW[2853 + j];
        if (j < 2)  wsW[4096 + 1624 + j] = wsW[2885 + j];
        if (j == 0) {
            float a0=wsW[2848],a1=wsW[2849],a2=wsW[2850],a3=wsW[2851],a4=wsW[2852];
            float am = fmaxf(fmaxf(fmaxf(a0,a1),fmaxf(a2,a3)),a4);
            float e0=__expf(a0-am),e1=__expf(a1-am),e2=__expf(a2-am),
                  e3=__expf(a3-am),e4=__expf(a4-am);
            float inv = 1.f/(e0+e1+e2+e3+e4);
            wsW[4096+1584+0]=e0*inv; wsW[4096+1584+1]=e1*inv;
            wsW[4096+1584+2]=e2*inv; wsW[4096+1584+3]=e3*inv;
            wsW[4096+1584+4]=e4*inv;
        }
    }
}

__global__ __launch_bounds__(256)
void k_deg(const int* __restrict__ dst, int* __restrict__ deg, int E)
{
    int e = blockIdx.x*256 + threadIdx.x;
    if (e < E) atomicAdd(&deg[dst[e]], 1);
}

__global__ __launch_bounds__(256)
void k_scan_a(const int* __restrict__ deg, float* __restrict__ dis,
              float* __restrict__ dinv, int* __restrict__ bsum, int N)
{
    __shared__ int sm[256];
    int i = blockIdx.x*256 + threadIdx.x;
    int c = (i < N) ? deg[i] : 0;
    if (i < N) {
        float d = (float)(c + 1);
        dis[i]  = rsqrtf(d);
        dinv[i] = 1.0f / d;
    }
    sm[threadIdx.x] = c; __syncthreads();
    for (int s = 128; s > 0; s >>= 1) {
        if (threadIdx.x < s) sm[threadIdx.x] += sm[threadIdx.x + s];
        __syncthreads();
    }
    if (threadIdx.x == 0) bsum[blockIdx.x] = sm[0];
}

__global__ void k_scan_b(const int* __restrict__ bsum, int* __restrict__ boff, int nb)
{
    __shared__ int sm[512];
    int t = threadIdx.x;
    int v = (t < nb) ? bsum[t] : 0;
    sm[t] = v; __syncthreads();
    for (int s = 1; s < 512; s <<= 1) {
        int add = (t >= s) ? sm[t - s] : 0;
        __syncthreads();
        sm[t] += add;
        __syncthreads();
    }
    if (t < nb) boff[t] = sm[t] - v;   // exclusive
}

__global__ __launch_bounds__(256)
void k_scan_c(const int* __restrict__ deg, const int* __restrict__ boff,
              int* __restrict__ row_start, int* __restrict__ cursor, int N, int E)
{
    __shared__ int sm[256];
    int t = threadIdx.x;
    int i = blockIdx.x*256 + t;
    int c = (i < N) ? deg[i] : 0;
    sm[t] = c; __syncthreads();
    for (int s = 1; s < 256; s <<= 1) {
        int add = (t >= s) ? sm[t - s] : 0;
        __syncthreads();
        sm[t] += add;
        __syncthreads();
    }
    int rs = boff[blockIdx.x] + sm[t] - c;
    if (i < N) {
        row_start[i] = rs;
        cursor[i]    = rs;
        if (i == N - 1) row_start[N] = rs + c;
    }
}

__global__ __launch_bounds__(256)
void k_fill(const int* __restrict__ src, const int* __restrict__ dst,
            const float* __restrict__ dis, int* __restrict__ cursor,
            int2* __restrict__ csr, int E)
{
    int e = blockIdx.x*256 + threadIdx.x;
    if (e < E) {
        int s = src[e], d = dst[e];
        int pos = atomicAdd(&cursor[d], 1);
        csr[pos] = make_int2(s, __float_as_int(dis[s]));
    }
}

// repack x [t][N][10] -> xr8 fp8 rows [i][64B] (16 u32; slice chunk 3 u32 at t*3)
__global__ __launch_bounds__(256, 4)
void k_repack(const void* __restrict__ x, const int* __restrict__ flagp,
              u32* __restrict__ xr, int N)
{
    int tid = blockIdx.x*256 + threadIdx.x;
    if (tid >= N*5) return;
    int i = tid / 5, t = tid - i*5;
    float f[10];
    if (flagp[0]) {
        const u32* xb = (const u32*)x;
        size_t b = ((size_t)t*N + i)*5;
        #pragma unroll
        for (int m = 0; m < 5; m++) {
            u32 u = xb[b + m];
            f[2*m] = bflo(u); f[2*m+1] = bfhi(u);
        }
    } else {
        const float* xf = (const float*)x + ((size_t)t*N + i)*10;
        #pragma unroll
        for (int m = 0; m < 10; m++) f[m] = xf[m];
    }
    u32* orow = xr + (size_t)i*16 + t*3;
    orow[0] = f8pack4(f[0], f[1], f[2], f[3]);
    orow[1] = f8pack4(f[4], f[5], f[6], f[7]);
    orow[2] = f8enc(f[8]) | (f8enc(f[9]) << 8);
}

// accumulate 10 fp8 (3 u32, last half-used) scaled by wg
__device__ __forceinline__ void acc10f8(u32 a, u32 b, u32 c, float wg,
                                        float* __restrict__ acc)
{
    acc[0] += wg*f8dec(a & 0xffu);        acc[1] += wg*f8dec((a >> 8) & 0xffu);
    acc[2] += wg*f8dec((a >> 16) & 0xffu); acc[3] += wg*f8dec(a >> 24);
    acc[4] += wg*f8dec(b & 0xffu);        acc[5] += wg*f8dec((b >> 8) & 0xffu);
    acc[6] += wg*f8dec((b >> 16) & 0xffu); acc[7] += wg*f8dec(b >> 24);
    acc[8] += wg*f8dec(c & 0xffu);        acc[9] += wg*f8dec((c >> 8) & 0xffu);
}

// pass 1: per (i,t), i-major. gather fp8 x-rows (1 cache line each), relu(@W1+b1)
// -> bufA8 fp8 [i][80B] (20 u32; slice chunk = uint4 at t*4)
__global__ __launch_bounds__(256, 4)
void k_g1(const u32* __restrict__ xr, const float* __restrict__ dis,
          const float* __restrict__ dinv, const int* __restrict__ row_start,
          const int2* __restrict__ csr, const float* __restrict__ wsW,
          u32* __restrict__ B, int N)
{
    __shared__ float w[176];
    for (int j = threadIdx.x; j < 176; j += 256) w[j] = wsW[j];
    __syncthreads();
    int tid = blockIdx.x*256 + threadIdx.x;
    if (tid >= N*5) return;
    int i = tid / 5, t = tid - i*5;

    float acc[10];
    float dd = dis[i], di = dinv[i];
    int rs = row_start[i], re = row_start[i+1];

    {
        const u32* p = xr + (size_t)i*16 + t*3;
        u32 a = p[0], b = p[1], c = p[2];
        #pragma unroll
        for (int m = 0; m < 10; m++) acc[m] = 0.f;
        acc10f8(a, b, c, di, acc);
    }
    int k = rs;
    for (; k + 1 < re; k += 2) {
        int2 s0 = csr[k], s1 = csr[k+1];
        float w0 = dd*__int_as_float(s0.y), w1 = dd*__int_as_float(s1.y);
        const u32* p0 = xr + (size_t)s0.x*16 + t*3;
        const u32* p1 = xr + (size_t)s1.x*16 + t*3;
        u32 a0 = p0[0], b0 = p0[1], c0 = p0[2];
        u32 a1 = p1[0], b1 = p1[1], c1 = p1[2];
        acc10f8(a0, b0, c0, w0, acc);
        acc10f8(a1, b1, c1, w1, acc);
    }
    if (k < re) {
        int2 sw = csr[k];
        float wg = dd * __int_as_float(sw.y);
        const u32* p = xr + (size_t)sw.x*16 + t*3;
        u32 a = p[0], b = p[1], c = p[2];
        acc10f8(a, b, c, wg, acc);
    }

    float hh[16];
    #pragma unroll
    for (int jb = 0; jb < 4; jb++) {
        float4 h = ((const float4*)&w[160])[jb];
        #pragma unroll
        for (int f = 0; f < 10; f++) {
            float4 wv = ((const float4*)w)[f*4 + jb];
            h.x += acc[f]*wv.x; h.y += acc[f]*wv.y;
            h.z += acc[f]*wv.z; h.w += acc[f]*wv.w;
        }
        hh[jb*4+0] = fmaxf(h.x, 0.f); hh[jb*4+1] = fmaxf(h.y, 0.f);
        hh[jb*4+2] = fmaxf(h.z, 0.f); hh[jb*4+3] = fmaxf(h.w, 0.f);
    }
    uint4 o = make_uint4(f8pack4(hh[0],hh[1],hh[2],hh[3]),
                         f8pack4(hh[4],hh[5],hh[6],hh[7]),
                         f8pack4(hh[8],hh[9],hh[10],hh[11]),
                         f8pack4(hh[12],hh[13],hh[14],hh[15]));
    *((uint4*)(B + (size_t)i*20 + t*4)) = o;
}

// accumulate 16 fp8 (one uint4) scaled by wg
__device__ __forceinline__ void acc16f8(uint4 v, float wg, float* __restrict__ acc)
{
    u32 w0 = v.x, w1 = v.y, w2 = v.z, w3 = v.w;
    acc[0]  += wg*f8dec(w0 & 0xffu);        acc[1]  += wg*f8dec((w0 >> 8) & 0xffu);
    acc[2]  += wg*f8dec((w0 >> 16) & 0xffu); acc[3]  += wg*f8dec(w0 >> 24);
    acc[4]  += wg*f8dec(w1 & 0xffu);        acc[5]  += wg*f8dec((w1 >> 8) & 0xffu);
    acc[6]  += wg*f8dec((w1 >> 16) & 0xffu); acc[7]  += wg*f8dec(w1 >> 24);
    acc[8]  += wg*f8dec(w2 & 0xffu);        acc[9]  += wg*f8dec((w2 >> 8) & 0xffu);
    acc[10] += wg*f8dec((w2 >> 16) & 0xffu); acc[11] += wg*f8dec(w2 >> 24);
    acc[12] += wg*f8dec(w3 & 0xffu);        acc[13] += wg*f8dec((w3 >> 8) & 0xffu);
    acc[14] += wg*f8dec((w3 >> 16) & 0xffu); acc[15] += wg*f8dec(w3 >> 24);
}

// unroll-4 gather of fp8 16-feature chunks from rows [i][80B]
__device__ __forceinline__ void gather16f8(const u32* __restrict__ Fin,
                                           const int2* __restrict__ csr,
                                           int rs, int re, int t, float dd,
                                           float* __restrict__ acc)
{
    int k = rs;
    for (; k + 3 < re; k += 4) {
        int2 s0 = csr[k], s1 = csr[k+1], s2 = csr[k+2], s3 = csr[k+3];
        float w0 = dd*__int_as_float(s0.y), w1 = dd*__int_as_float(s1.y);
        float w2 = dd*__int_as_float(s2.y), w3 = dd*__int_as_float(s3.y);
        uint4 v0 = *((const uint4*)(Fin + (size_t)s0.x*20 + t*4));
        uint4 v1 = *((const uint4*)(Fin + (size_t)s1.x*20 + t*4));
        uint4 v2 = *((const uint4*)(Fin + (size_t)s2.x*20 + t*4));
        uint4 v3 = *((const uint4*)(Fin + (size_t)s3.x*20 + t*4));
        acc16f8(v0, w0, acc); acc16f8(v1, w1, acc);
        acc16f8(v2, w2, acc); acc16f8(v3, w3, acc);
    }
    for (; k < re; k++) {
        int2 sw = csr[k];
        float wg = dd*__int_as_float(sw.y);
        uint4 v = *((const uint4*)(Fin + (size_t)sw.x*20 + t*4));
        acc16f8(v, wg, acc);
    }
}

// pass 2: gather fp8, relu(@W2+b2) -> bufB8 fp8 [i][80B]
__global__ __launch_bounds__(256, 4)
void k_g2(const u32* __restrict__ Fin, const float* __restrict__ dis,
          const float* __restrict__ dinv, const int* __restrict__ row_start,
          const int2* __restrict__ csr, const float* __restrict__ wsW,
          u32* __restrict__ B, int N)
{
    __shared__ float w[272];
    for (int j = threadIdx.x; j < 272; j += 256) w[j] = wsW[176 + j];
    __syncthreads();
    int tid = blockIdx.x*256 + threadIdx.x;
    if (tid >= N*5) return;
    int i = tid / 5, t = tid - i*5;

    float dd = dis[i], di = dinv[i];
    int rs = row_start[i], re = row_start[i+1];

    float acc[16];
    #pragma unroll
    for (int j = 0; j < 16; j++) acc[j] = 0.f;
    acc16f8(*((const uint4*)(Fin + (size_t)i*20 + t*4)), di, acc);
    gather16f8(Fin, csr, rs, re, t, dd, acc);

    float hh[16];
    #pragma unroll
    for (int jb = 0; jb < 4; jb++) {
        float4 h = ((const float4*)&w[256])[jb];
        #pragma unroll
        for (int f = 0; f < 16; f++) {
            float4 wv = ((const float4*)w)[f*4 + jb];
            h.x += acc[f]*wv.x; h.y += acc[f]*wv.y;
            h.z += acc[f]*wv.z; h.w += acc[f]*wv.w;
        }
        hh[jb*4+0] = fmaxf(h.x, 0.f); hh[jb*4+1] = fmaxf(h.y, 0.f);
        hh[jb*4+2] = fmaxf(h.z, 0.f); hh[jb*4+3] = fmaxf(h.w, 0.f);
    }
    uint4 o = make_uint4(f8pack4(hh[0],hh[1],hh[2],hh[3]),
                         f8pack4(hh[4],hh[5],hh[6],hh[7]),
                         f8pack4(hh[8],hh[9],hh[10],hh[11]),
                         f8pack4(hh[12],hh[13],hh[14],hh[15]));
    *((uint4*)(B + (size_t)i*20 + t*4)) = o;
}

// pass 3: gather fp8 -> bufC bf16 [i][80] (GRU input)
__global__ __launch_bounds__(256, 4)
void k_g3(const u32* __restrict__ Fin, const float* __restrict__ dis,
          const float* __restrict__ dinv, const int* __restrict__ row_start,
          const int2* __restrict__ csr, u32* __restrict__ B, int N)
{
    int tid = blockIdx.x*256 + threadIdx.x;
    if (tid >= N*5) return;
    int i = tid / 5, t = tid - i*5;

    float dd = dis[i], di = dinv[i];
    int rs = row_start[i], re = row_start[i+1];

    float acc[16];
    #pragma unroll
    for (int j = 0; j < 16; j++) acc[j] = 0.f;
    acc16f8(*((const uint4*)(Fin + (size_t)i*20 + t*4)), di, acc);
    gather16f8(Fin, csr, rs, re, t, dd, acc);

    u32* orow = B + (size_t)i*40 + t*8;
    uint4 o0 = make_uint4(packbf(acc[0],acc[1]), packbf(acc[2],acc[3]),
                          packbf(acc[4],acc[5]), packbf(acc[6],acc[7]));
    uint4 o1 = make_uint4(packbf(acc[8],acc[9]), packbf(acc[10],acc[11]),
                          packbf(acc[12],acc[13]), packbf(acc[14],acc[15]));
    ((uint4*)orow)[0] = o0;
    ((uint4*)orow)[1] = o1;
}

// GRU + attention + FC + log_softmax. One thread per node; Pf bf16 [i][80].
__global__ __launch_bounds__(256, 3)
void k_gru(const u32* __restrict__ C, const float* __restrict__ wsW,
           const int* __restrict__ flagp, void* __restrict__ out, int N)
{
    __shared__ __align__(16) float sm[1632];
    for (int j = threadIdx.x; j < 1632; j += 256) sm[j] = wsW[4096 + j];
    __syncthreads();

    int i = blockIdx.x*256 + threadIdx.x;
    if (i >= N) return;

    const float4* Az = (const float4*)&sm[0];
    const float4* Ar = (const float4*)&sm[256];
    const float4* Ah = (const float4*)&sm[512];
    const float4* Lz = (const float4*)&sm[768];
    const float4* Lr = (const float4*)&sm[1024];
    const float4* Lh = (const float4*)&sm[1280];

    float H[16];
    #pragma unroll
    for (int j = 0; j < 16; j++) H[j] = 0.f;
    float z0 = sm[1624], z1 = sm[1625];

    for (int t = 0; t < 5; t++) {
        float pf[16];
        {
            const u32* p = C + (size_t)i*40 + t*8;
            uint4 a = ((const uint4*)p)[0];
            uint4 b = ((const uint4*)p)[1];
            pf[0]=bflo(a.x); pf[1]=bfhi(a.x); pf[2]=bflo(a.y); pf[3]=bfhi(a.y);
            pf[4]=bflo(a.z); pf[5]=bfhi(a.z); pf[6]=bflo(a.w); pf[7]=bfhi(a.w);
            pf[8]=bflo(b.x); pf[9]=bfhi(b.x); pf[10]=bflo(b.y); pf[11]=bfhi(b.y);
            pf[12]=bflo(b.z); pf[13]=bfhi(b.z); pf[14]=bflo(b.w); pf[15]=bfhi(b.w);
        }

        float Zg[16];
        #pragma unroll
        for (int jb = 0; jb < 4; jb++) {
            float4 a = ((const float4*)&sm[1536])[jb];
            #pragma unroll
            for (int k = 0; k < 16; k++) {
                float pp = pf[k]; float4 wv = Az[k*4+jb];
                a.x += pp*wv.x; a.y += pp*wv.y; a.z += pp*wv.z; a.w += pp*wv.w;
            }
            #pragma unroll
            for (int k = 0; k < 16; k++) {
                float h = H[k]; float4 wv = Lz[k*4+jb];
                a.x += h*wv.x; a.y += h*wv.y; a.z += h*wv.z; a.w += h*wv.w;
            }
            Zg[jb*4+0]=sigm(a.x); Zg[jb*4+1]=sigm(a.y);
            Zg[jb*4+2]=sigm(a.z); Zg[jb*4+3]=sigm(a.w);
        }
        float HR[16];
        #pragma unroll
        for (int jb = 0; jb < 4; jb++) {
            float4 a = ((const float4*)&sm[1552])[jb];
            #pragma unroll
            for (int k = 0; k < 16; k++) {
                float pp = pf[k]; float4 wv = Ar[k*4+jb];
                a.x += pp*wv.x; a.y += pp*wv.y; a.z += pp*wv.z; a.w += pp*wv.w;
            }
            #pragma unroll
            for (int k = 0; k < 16; k++) {
                float h = H[k]; float4 wv = Lr[k*4+jb];
                a.x += h*wv.x; a.y += h*wv.y; a.z += h*wv.z; a.w += h*wv.w;
            }
            HR[jb*4+0]=H[jb*4+0]*sigm(a.x); HR[jb*4+1]=H[jb*4+1]*sigm(a.y);
            HR[jb*4+2]=H[jb*4+2]*sigm(a.z); HR[jb*4+3]=H[jb*4+3]*sigm(a.w);
        }
        #pragma unroll
        for (int jb = 0; jb < 4; jb++) {
            float4 a = ((const float4*)&sm[1568])[jb];
            #pragma unroll
            for (int k = 0; k < 16; k++) {
                float pp = pf[k]; float4 wv = Ah[k*4+jb];
                a.x += pp*wv.x; a.y += pp*wv.y; a.z += pp*wv.z; a.w += pp*wv.w;
            }
            #pragma unroll
            for (int k = 0; k < 16; k++) {
                float h = HR[k]; float4 wv = Lh[k*4+jb];
                a.x += h*wv.x; a.y += h*wv.y; a.z += h*wv.z; a.w += h*wv.w;
            }
            #pragma unroll
            for (int q = 0; q < 4; q++) {
                int j = jb*4 + q;
                float v = (q==0)?a.x:(q==1)?a.y:(q==2)?a.z:a.w;
                v = fminf(fmaxf(v, -15.f), 15.f);
                float ex = __expf(2.f*v);
                float th = (ex - 1.f) / (ex + 1.f);
                float z = Zg[j];
                H[j] = z*H[j] + (1.f - z)*th;
            }
        }
        float pr = sm[1584 + t];
        float s0 = 0.f, s1 = 0.f;
        #pragma unroll
        for (int k = 0; k < 16; k++) {
            s0 += H[k]*sm[1592 + k*2];
            s1 += H[k]*sm[1592 + k*2 + 1];
        }
        z0 += pr*s0; z1 += pr*s1;
    }

    float mm = fmaxf(z0, z1);
    float l  = __logf(__expf(z0-mm) + __expf(z1-mm));
    float o0 = z0 - mm - l, o1 = z1 - mm - l;
    if (flagp[0]) {
        ((u32*)out)[i] = packbf(o0, o1);
    } else {
        ((float2*)out)[i] = make_float2(o0, o1);
    }
}

extern "C" void kernel_launch(void* const* d_in, const int* in_sizes, int n_in,
                              void* d_out, int out_size, void* d_ws, size_t ws_size,
                              hipStream_t stream)
{
    const void* x   = d_in[0];
    const int* src  = (const int*)d_in[1];
    const int* dst  = (const int*)d_in[2];
    int N = in_sizes[0] / 50;     // T*F_IN = 50
    int E = in_sizes[1];

    char* ws = (char*)d_ws;
    size_t off = 0;
    auto alloc = [&](size_t bytes) -> void* {
        void* p = ws + off;
        off = (off + bytes + 255) & ~(size_t)255;
        return p;
    };
    int*   flagp     = (int*)  alloc(64);
    float* wsW       = (float*)alloc(8192*4);
    int*   deg       = (int*)  alloc((size_t)N*4);
    float* dis       = (float*)alloc((size_t)N*4);
    float* dinv      = (float*)alloc((size_t)N*4);
    int*   row_start = (int*)  alloc(((size_t)N+1)*4);
    int*   cursor    = (int*)  alloc((size_t)N*4);
    int*   bsum      = (int*)  alloc(4096);
    int*   boff      = (int*)  alloc(4096);
    int2*  csr       = (int2*) alloc((size_t)E*8);
    u32*   xr8       = (u32*)  alloc((size_t)N*16*4);   // fp8 x rows [i][64B]
    u32*   bufA8     = (u32*)  alloc((size_t)N*20*4);   // fp8 [i][80B]
    u32*   bufB8     = (u32*)  alloc((size_t)N*20*4);
    u32*   bufC      = (u32*)  alloc((size_t)N*40*4);   // bf16 [i][80]

    int nb  = (N + 255) / 256;
    int gE  = (E + 255) / 256;
    int g5  = ((size_t)N*5 + 255) / 256;

    hipMemsetAsync(deg, 0, (size_t)N*4, stream);

    WPtrs wp;
    for (int a = 0; a < 19; a++) wp.p[a] = d_in[3 + a];
    k_prep<<<1, 256, 0, stream>>>(x, wp, flagp, wsW);

    k_deg   <<<gE, 256, 0, stream>>>(dst, deg, E);
    k_scan_a<<<nb, 256, 0, stream>>>(deg, dis, dinv, bsum, N);
    k_scan_b<<<1, 512, 0, stream>>>(bsum, boff, nb);
    k_scan_c<<<nb, 256, 0, stream>>>(deg, boff, row_start, cursor, N, E);
    k_fill  <<<gE, 256, 0, stream>>>(src, dst, dis, cursor, csr, E);

    k_repack<<<g5, 256, 0, stream>>>(x, flagp, xr8, N);
    k_g1    <<<g5, 256, 0, stream>>>(xr8, dis, dinv, row_start, csr, wsW, bufA8, N);
    k_g2    <<<g5, 256, 0, stream>>>(bufA8, dis, dinv, row_start, csr, wsW, bufB8, N);
    k_g3    <<<g5, 256, 0, stream>>>(bufB8, dis, dinv, row_start, csr, bufC, N);
    k_gru   <<<nb, 256, 0, stream>>>(bufC, wsW, flagp, d_out, N);
}